// Round 11
// baseline (138.465 us; speedup 1.0000x reference)
//
#include <hip/hip_runtime.h>
#include <math.h>

#define BB 8
#define CC 128
#define NN 4096   // W*H

typedef _Float16 f16;
typedef __fp16 h16x2 __attribute__((ext_vector_type(2)));
typedef _Float16 f16x4v __attribute__((ext_vector_type(4)));
typedef _Float16 f16x8 __attribute__((ext_vector_type(8)));
typedef float f32x4v __attribute__((ext_vector_type(4)));
typedef float f32x16 __attribute__((ext_vector_type(16)));

#if __has_builtin(__builtin_amdgcn_exp2f)
#define EXP2(x) __builtin_amdgcn_exp2f(x)
#else
#define EXP2(x) __expf((x)*0.69314718056f)
#endif

// Q rows pre-scaled by 0.25*log2(e): softmax exp is one native v_exp_f32;
// the -SHIFT bias rides in the MFMA C operand (loop-invariant regs).
#define QSCALE 0.360673760222f   // 0.25 * log2(e)
#define SHIFT  5.770780163555f   // 4.0 * log2(e)

// Wf scratch lives in the tail of d_out (attn rewrites d_out afterwards).
#define WF_BYTES 65536

// ---------------------------------------------------------------------------
// prep: stack Wq*QSCALE (rows 0-15), Wk (16-31), Wv (32-159) as f16 in
// 32x32x16 A-fragment order. biasS f32[160] likewise stacked.
// ---------------------------------------------------------------------------
__global__ __launch_bounds__(256)
void prep_kernel(const float* __restrict__ Wq, const float* __restrict__ bq,
                 const float* __restrict__ Wk, const float* __restrict__ bk,
                 const float* __restrict__ Wv, const float* __restrict__ bv,
                 f16* __restrict__ Wf, float* __restrict__ biasS)
{
    const int tg = blockIdx.x*256 + threadIdx.x;   // 0..2559
    if (tg < 2560) {
        const int mt = tg >> 9, ks = (tg >> 6) & 7, l = tg & 63;
        const int n32 = l & 31, h = l >> 5;
        const int r = mt*32 + n32;
        f16x8 v8;
        #pragma unroll
        for (int i = 0; i < 8; i++) {
            int c = ks*16 + 8*h + i;
            float wv_;
            if (r < 16)      wv_ = QSCALE * Wq[r*CC + c];
            else if (r < 32) wv_ = Wk[(r-16)*CC + c];
            else             wv_ = Wv[(r-32)*CC + c];
            v8[i] = (f16)wv_;
        }
        *(f16x8*)&Wf[(size_t)tg*8] = v8;
    }
    if (blockIdx.x == 0 && threadIdx.x < 160) {
        int r = threadIdx.x;
        biasS[r] = r < 16 ? QSCALE*bq[r] : (r < 32 ? bk[r-16] : bv[r-32]);
    }
}

// ---------------------------------------------------------------------------
// Projection as MFMA mini-GEMM: OUT[160][128px] = Wst(160x128) * x(128x128px).
// grid 256 (b = bx&7, pt = bx>>3), block 256 = 4 waves. Non-temporal x loads.
// Epilogue: Qt/Kt pixel-major; V via LDS -> sigma-ordered Vf:
//   Vf[b][kt64][frag=kc*4+ct][l][i] =
//     V[c=ct*32+(l&31)][key=kt64*64 + kc*16 + (i&3)+8*(i>>2)+4*(l>>5)]
// ---------------------------------------------------------------------------
__global__ __launch_bounds__(256)
void proj_kernel(const float* __restrict__ x, const f16* __restrict__ Wf,
                 const float* __restrict__ biasS,
                 f16* __restrict__ Qt, f16* __restrict__ Kt, f16* __restrict__ Vf)
{
    __shared__ __align__(16) f16 Vl[CC*140];   // 35 KB, stride 140 halfs

    const int tid  = threadIdx.x;
    const int lane = tid & 63;
    const int wv   = tid >> 6;
    const int b    = blockIdx.x & 7;
    const int pt   = blockIdx.x >> 3;      // 0..31
    const int n32  = lane & 31;
    const int half = lane >> 5;
    const int p    = pt*128 + wv*32 + n32;

    const float* xp = x + (size_t)b*CC*NN + p;
    f16x8 xf[8];
    #pragma unroll
    for (int ks = 0; ks < 8; ks++) {
        float xv[8];
        #pragma unroll
        for (int i = 0; i < 8; i++)
            xv[i] = __builtin_nontemporal_load(&xp[(size_t)(ks*16 + 8*half + i)*NN]);
        #pragma unroll
        for (int i = 0; i < 8; i++) xf[ks][i] = (f16)xv[i];
    }

    f32x16 acc[5];
    #pragma unroll
    for (int mt = 0; mt < 5; mt++) acc[mt] = (f32x16)0.0f;
    #pragma unroll
    for (int ks = 0; ks < 8; ks++) {
        #pragma unroll
        for (int mt = 0; mt < 5; mt++) {
            f16x8 wfr = *(const f16x8*)&Wf[((size_t)(mt*8 + ks)*64 + lane)*8];
            acc[mt] = __builtin_amdgcn_mfma_f32_32x32x16_f16(wfr, xf[ks], acc[mt], 0, 0, 0);
        }
    }

    #pragma unroll
    for (int mt = 0; mt < 5; mt++) {
        #pragma unroll
        for (int q = 0; q < 4; q++) {
            float4 b4 = *(const float4*)&biasS[mt*32 + q*8 + 4*half];
            acc[mt][q*4+0] += b4.x; acc[mt][q*4+1] += b4.y;
            acc[mt][q*4+2] += b4.z; acc[mt][q*4+3] += b4.w;
        }
    }

    // mt0: rows 0-15 = Q, 16-31 = K
    {
        size_t qkoff = ((size_t)b*NN + p)*16;
        f16x4v s0, s1, s2, s3;
        #pragma unroll
        for (int i = 0; i < 4; i++) {
            s0[i] = (f16)acc[0][i];    s1[i] = (f16)acc[0][4+i];
            s2[i] = (f16)acc[0][8+i];  s3[i] = (f16)acc[0][12+i];
        }
        *(f16x4v*)&Qt[qkoff + 4*half]     = s0;
        *(f16x4v*)&Qt[qkoff + 8 + 4*half] = s1;
        *(f16x4v*)&Kt[qkoff + 4*half]     = s2;
        *(f16x4v*)&Kt[qkoff + 8 + 4*half] = s3;
    }

    // mt1-4: V channels -> LDS [c][local pixel]
    #pragma unroll
    for (int mt = 1; mt < 5; mt++) {
        #pragma unroll
        for (int g = 0; g < 16; g++) {
            int c = (mt-1)*32 + (g & 3) + 8*(g >> 2) + 4*half;
            Vl[c*140 + wv*32 + n32] = (f16)acc[mt][g];
        }
    }
    __syncthreads();

    // sigma-ordered Vf writeout
    #pragma unroll
    for (int pass = 0; pass < 8; pass++) {
        int item = pass*256 + tid;
        int l    = item & 63;
        int f    = (item >> 6) & 15;       // c16*4 + ct
        int ktl  = item >> 10;             // 0..1 (64-px tile within block)
        int c16  = f >> 2, ct = f & 3;
        int li   = l & 31, h2 = l >> 5;
        const f16* src = &Vl[(ct*32 + li)*140 + ktl*64 + c16*16 + 4*h2];
        f16x4v lo = *(const f16x4v*)&src[0];
        f16x4v hi = *(const f16x4v*)&src[8];
        f16x8 v8;
        #pragma unroll
        for (int i = 0; i < 4; i++) { v8[i] = lo[i]; v8[4+i] = hi[i]; }
        int ktg = pt*2 + ktl;              // 64-key tile index
        *(f16x8*)&Vf[((((size_t)b*64 + ktg)*16 + c16*4 + ct)*64 + l)*8] = v8;
    }
}

// ---------------------------------------------------------------------------
// Attention: LDS-free, barrier-free, SOFTWARE-PIPELINED main loop.
// grid 1024 (b = bx&7, qt = bx>>3 -> 32 queries), block 256 = 4 waves = 4-way
// key split (wave wv: kt = wv, wv+4, ...). S^T trick + sigma-in-Vf.
// r10 restructure: body computes St(kt+4) FIRST, then interleaves PV(kt)
// MFMAs (pf from previous body) with exp/pack(kt+4) per kc-group -> PV and
// exp have no intra-body dependency, so MFMA pipe and VALU overlap (m114).
// P packing via cvt_pkrtz (1 inst / 2 elements). Last tile peeled (PV only).
// ---------------------------------------------------------------------------
__global__ __launch_bounds__(256, 2)
void attn_kernel(const f16* __restrict__ Qt, const f16* __restrict__ Kt,
                 const f16* __restrict__ Vf, float* __restrict__ out)
{
    __shared__ __align__(16) unsigned char lds_raw[27776];
    // [0, 27648): 3 combine regions (64 lanes x 144B) / later f32 Tb[128][36]
    // [27648, 27776): ls_inv[32] f32

    const int tid  = threadIdx.x;
    const int lane = tid & 63;
    const int wv   = tid >> 6;
    const int b    = blockIdx.x & 7;
    const int qt   = blockIdx.x >> 3;
    const int q0   = qt*32;
    const int n32  = lane & 31;
    const int half = lane >> 5;

    const f16* vb = Vf + (size_t)b*64*16*512;
    const f16* kb = Kt + (size_t)b*NN*16;
    const f16x8 qf = *(const f16x8*)&Qt[((size_t)b*NN + q0 + n32)*16 + half*8];
    const f32x16 negS = (f32x16)(-SHIFT);

    f32x16 of[4];
    #pragma unroll
    for (int ct = 0; ct < 4; ct++) of[ct] = (f32x16)0.0f;
    float ps[4] = {0.f, 0.f, 0.f, 0.f};

    // ---- prologue: tile wv fully through exp; K(wv+4) prefetched ----
    f16x8 kf0 = *(const f16x8*)&kb[((size_t)wv*64 + n32)*16 + half*8];
    f16x8 kf1 = *(const f16x8*)&kb[((size_t)wv*64 + 32 + n32)*16 + half*8];
    f16x8 vpf[16];
    {
        const f16* vt = vb + (size_t)wv*8192;
        #pragma unroll
        for (int i = 0; i < 16; i++)
            vpf[i] = *(const f16x8*)&vt[((size_t)i*64 + lane)*8];
    }
    f16x8 pf[4];
    {
        f32x16 St0 = __builtin_amdgcn_mfma_f32_32x32x16_f16(kf0, qf, negS, 0, 0, 0);
        f32x16 St1 = __builtin_amdgcn_mfma_f32_32x32x16_f16(kf1, qf, negS, 0, 0, 0);
        kf0 = *(const f16x8*)&kb[((size_t)(wv+4)*64 + n32)*16 + half*8];
        kf1 = *(const f16x8*)&kb[((size_t)(wv+4)*64 + 32 + n32)*16 + half*8];
        #pragma unroll
        for (int j = 0; j < 4; j++) {
            float a0 = EXP2(St0[2*j]),   a1 = EXP2(St0[2*j+1]);
            float b0 = EXP2(St0[8+2*j]), b1 = EXP2(St0[8+2*j+1]);
            float c0 = EXP2(St1[2*j]),   c1 = EXP2(St1[2*j+1]);
            float d0 = EXP2(St1[8+2*j]), d1 = EXP2(St1[8+2*j+1]);
            ps[(2*j) & 3] += a0 + b0 + c0 + d0;
            ps[(2*j+1) & 3] += a1 + b1 + c1 + d1;
            ((h16x2*)&pf[0])[j] = __builtin_amdgcn_cvt_pkrtz(a0, a1);
            ((h16x2*)&pf[1])[j] = __builtin_amdgcn_cvt_pkrtz(b0, b1);
            ((h16x2*)&pf[2])[j] = __builtin_amdgcn_cvt_pkrtz(c0, c1);
            ((h16x2*)&pf[3])[j] = __builtin_amdgcn_cvt_pkrtz(d0, d1);
        }
    }

    // ---- pipelined main loop: PV(kt) overlapped with St/exp(kt+4) ----
    for (int kt = wv; kt + 4 < NN/64; kt += 4) {
        const int ktn  = kt + 4;
        const int ktnn = (ktn + 4 < NN/64) ? ktn + 4 : ktn;

        // St for tile ktn (kf holds K(ktn))
        f32x16 St0 = __builtin_amdgcn_mfma_f32_32x32x16_f16(kf0, qf, negS, 0, 0, 0);
        f32x16 St1 = __builtin_amdgcn_mfma_f32_32x32x16_f16(kf1, qf, negS, 0, 0, 0);
        kf0 = *(const f16x8*)&kb[((size_t)ktnn*64 + n32)*16 + half*8];
        kf1 = *(const f16x8*)&kb[((size_t)ktnn*64 + 32 + n32)*16 + half*8];

        const f16* vtn = vb + (size_t)ktn*8192;
        f16x8 pfn[4];
        #pragma unroll
        for (int kc = 0; kc < 4; kc++) {
            // 4 PV MFMAs (tile kt) + V prefetch (tile ktn)
            #pragma unroll
            for (int ct = 0; ct < 4; ct++) {
                const int i = kc*4 + ct;
                f16x8 vc = vpf[i];
                vpf[i] = *(const f16x8*)&vtn[((size_t)i*64 + lane)*8];
                of[ct] = __builtin_amdgcn_mfma_f32_32x32x16_f16(pf[kc], vc, of[ct], 0, 0, 0);
            }
            // 8 exps of tile ktn (independent of the PV above -> co-issue)
            const int base = (kc & 1)*8;
            #pragma unroll
            for (int j = 0; j < 4; j++) {
                float e0 = (kc < 2) ? EXP2(St0[base + 2*j])   : EXP2(St1[base + 2*j]);
                float e1 = (kc < 2) ? EXP2(St0[base + 2*j+1]) : EXP2(St1[base + 2*j+1]);
                ps[(2*j) & 3]   += e0;
                ps[(2*j+1) & 3] += e1;
                ((h16x2*)&pfn[kc])[j] = __builtin_amdgcn_cvt_pkrtz(e0, e1);
            }
        }
        #pragma unroll
        for (int kc = 0; kc < 4; kc++) pf[kc] = pfn[kc];
    }

    // ---- peeled last tile: PV only ----
    #pragma unroll
    for (int kc = 0; kc < 4; kc++) {
        #pragma unroll
        for (int ct = 0; ct < 4; ct++)
            of[ct] = __builtin_amdgcn_mfma_f32_32x32x16_f16(pf[kc], vpf[kc*4 + ct], of[ct], 0, 0, 0);
    }

    // per-lane softmax denominator for query n32 (this wave's key subset)
    float ls = (ps[0] + ps[1]) + (ps[2] + ps[3]);
    ls += __shfl_xor(ls, 32);

    // ---- combine 4 key-split partials ----
    __syncthreads();
    if (wv != 0) {
        unsigned char* base = lds_raw + (size_t)(wv-1)*9216 + (size_t)lane*144;
        #pragma unroll
        for (int ct = 0; ct < 4; ct++) {
            #pragma unroll
            for (int h = 0; h < 2; h++) {
                f16x8 t;
                #pragma unroll
                for (int jj = 0; jj < 8; jj++) t[jj] = (f16)of[ct][h*8+jj];
                *(f16x8*)(base + ct*32 + h*16) = t;
            }
        }
        *(float*)(base + 128) = ls;
    }
    __syncthreads();
    if (wv == 0) {
        #pragma unroll
        for (int s2 = 0; s2 < 3; s2++) {
            unsigned char* base = lds_raw + (size_t)s2*9216 + (size_t)lane*144;
            #pragma unroll
            for (int ct = 0; ct < 4; ct++) {
                #pragma unroll
                for (int h = 0; h < 2; h++) {
                    f16x8 t = *(const f16x8*)(base + ct*32 + h*16);
                    #pragma unroll
                    for (int jj = 0; jj < 8; jj++) of[ct][h*8+jj] += (float)t[jj];
                }
            }
            ls += *(const float*)(base + 128);
        }
        float* ls_inv = (float*)(lds_raw + 27648);
        if (lane < 32) ls_inv[lane] = 1.f / ls;
        float invq[16];
        #pragma unroll
        for (int g = 0; g < 16; g++)
            invq[g] = ls_inv[(g & 3) + 8*(g >> 2) + 4*half];
        float* Tb = (float*)lds_raw;   // [128 c][36], aliases combine regions
        #pragma unroll
        for (int ct = 0; ct < 4; ct++) {
            #pragma unroll
            for (int g = 0; g < 16; g++) {
                int row = (g & 3) + 8*(g >> 2) + 4*half;
                Tb[(ct*32 + n32)*36 + row] = of[ct][g] * invq[g];
            }
        }
    }
    __syncthreads();
    {
        const float* Tb = (const float*)lds_raw;
        #pragma unroll
        for (int it = 0; it < 4; it++) {
            int idx = it*256 + tid;
            int c = idx >> 3, qq = idx & 7;
            f32x4v v = *(const f32x4v*)&Tb[c*36 + qq*4];
            __builtin_nontemporal_store(v,
                (f32x4v*)&out[((size_t)b*CC + c)*NN + q0 + qq*4]);
        }
    }
}

extern "C" void kernel_launch(void* const* d_in, const int* in_sizes, int n_in,
                              void* d_out, int out_size, void* d_ws, size_t ws_size,
                              hipStream_t stream) {
    const float* x  = (const float*)d_in[0];
    const float* Wq = (const float*)d_in[1];
    const float* bq = (const float*)d_in[2];
    const float* Wk = (const float*)d_in[3];
    const float* bk = (const float*)d_in[4];
    const float* Wv = (const float*)d_in[5];
    const float* bv = (const float*)d_in[6];
    float* out = (float*)d_out;

    // workspace: Qt,Kt f16 [B][N][16] (1MB each), Vf f16 sigma-fragments (8MB)
    f16* Qw = (f16*)d_ws;
    f16* Kw = Qw + (size_t)BB*NN*16;
    f16* Vw = Kw + (size_t)BB*NN*16;
    unsigned char* tail = (unsigned char*)d_out + (size_t)out_size*4 - WF_BYTES;
    f16*   Wf    = (f16*)tail;
    float* biasS = (float*)(tail + 49152);

    hipLaunchKernelGGL(prep_kernel, dim3(10), dim3(256), 0, stream,
                       Wq, bq, Wk, bk, Wv, bv, Wf, biasS);
    hipLaunchKernelGGL(proj_kernel, dim3(256), dim3(256), 0, stream,
                       x, Wf, biasS, Qw, Kw, Vw);
    hipLaunchKernelGGL(attn_kernel, dim3(1024), dim3(256), 0, stream,
                       Qw, Kw, Vw, out);
}